// Round 1
// baseline (15519.891 us; speedup 1.0000x reference)
//
#include <hip/hip_runtime.h>
#include <stdint.h>

// Problem constants (match reference)
#define B 128
#define S 256
#define T 256
#define EMBED 256
#define ENC 256
#define DEC 512
#define DOF 4

typedef __attribute__((ext_vector_type(8))) short bf16x8;   // 8 bf16 = 4 VGPRs (MFMA A/B frag)
typedef __attribute__((ext_vector_type(4))) float f32x4;    // MFMA C/D frag

static __device__ __forceinline__ float bf2f(unsigned short u){
  union{uint32_t u;float f;}c; c.u = ((uint32_t)u)<<16; return c.f;
}
static __device__ __forceinline__ unsigned short f2bf(float f){
  union{float f;uint32_t u;}c; c.f=f; uint32_t u=c.u;
  u += 0x7fffu + ((u>>16)&1u);  // round-to-nearest-even
  return (unsigned short)(u>>16);
}
static __device__ __forceinline__ void unp2(uint32_t w, float&a, float&b){
  union{uint32_t u;float f;}c1,c2; c1.u = w<<16; c2.u = w & 0xffff0000u; a=c1.f; b=c2.f;
}
static __device__ __forceinline__ float sigm(float x){ return 1.0f/(1.0f+__expf(-x)); }

// ---------------------------------------------------------------------------
// bf16 MFMA GEMM core: computes C tile (64 rows x 32 cols) at (m_base,n_base).
//   C[m][n] = sum_k A[m][k] * W[n][k]   (A = up to 3 row-major bf16 segments
//   concatenated along K, W = row-major (N x Ktot) bf16 "B^T" weights).
// Each segment length must be a multiple of 64 (BK). 256 threads, 4 waves 2x2,
// wave tile 32x16, 16x16x32 MFMA. smem needs 13824 bytes.
// ---------------------------------------------------------------------------
static __device__ __forceinline__ void gemm_tile(
    const unsigned short* __restrict__ s0, int l0, int ld0,
    const unsigned short* __restrict__ s1, int l1, int ld1,
    const unsigned short* __restrict__ s2, int l2, int ld2,
    const unsigned short* __restrict__ W, int ldw,
    int m_base, int n_base, char* smem, f32x4* acc)
{
  unsigned short* As = (unsigned short*)smem;     // 64 x 72 (pad 64->72 for banks)
  unsigned short* Bs = As + 64*72;                // 32 x 72
  const int tid  = threadIdx.x;
  const int lane = tid & 63;
  const int wid  = tid >> 6;
  const int wm = wid >> 1, wn = wid & 1;
  const int l16 = lane & 15, qd = lane >> 4;
  const int Ktot = l0 + l1 + l2;
  const int ar = tid >> 2, aco = (tid & 3) * 16;
  const int br = (tid & 127) >> 2, bco = (tid & 3) * 16;
  const bool loadB = (tid >= 128);

  for (int ktb = 0; ktb < Ktot; ktb += 64){
    const unsigned short* ap; int ld, kloc;
    if (ktb < l0)          { ap = s0; ld = ld0; kloc = ktb; }
    else if (ktb < l0 + l1){ ap = s1; ld = ld1; kloc = ktb - l0; }
    else                   { ap = s2; ld = ld2; kloc = ktb - l0 - l1; }
    const unsigned short* arow = ap + (size_t)(m_base + ar) * ld + kloc + aco;
    uint4 av0 = *(const uint4*)(arow);
    uint4 av1 = *(const uint4*)(arow + 8);
    uint4 bv0, bv1;
    if (loadB){
      const unsigned short* brow = W + (size_t)(n_base + br) * ldw + ktb + bco;
      bv0 = *(const uint4*)(brow);
      bv1 = *(const uint4*)(brow + 8);
    }
    __syncthreads();                 // protect previous iteration's frag reads
    *(uint4*)&As[ar*72 + aco]     = av0;
    *(uint4*)&As[ar*72 + aco + 8] = av1;
    if (loadB){
      *(uint4*)&Bs[br*72 + bco]     = bv0;
      *(uint4*)&Bs[br*72 + bco + 8] = bv1;
    }
    __syncthreads();
#pragma unroll
    for (int kh = 0; kh < 2; ++kh){
      const int ko = kh*32 + qd*8;
      bf16x8 a0 = *(bf16x8*)&As[(wm*32      + l16)*72 + ko];
      bf16x8 a1 = *(bf16x8*)&As[(wm*32 + 16 + l16)*72 + ko];
      bf16x8 bb = *(bf16x8*)&Bs[(wn*16      + l16)*72 + ko];
      acc[0] = __builtin_amdgcn_mfma_f32_16x16x32_bf16(a0, bb, acc[0], 0, 0, 0);
      acc[1] = __builtin_amdgcn_mfma_f32_16x16x32_bf16(a1, bb, acc[1], 0, 0, 0);
    }
  }
}

// ---------------------------------------------------------------------------
// LSTM gates GEMM + fused cell update. Weights pre-reordered row = j*4 + gate
// (gate order i,f,g,o), so a 32-wide N tile = 8 complete hidden units.
// ---------------------------------------------------------------------------
static __device__ __forceinline__ void lstm_step_body(
    const unsigned short* s0,int l0,int ld0,
    const unsigned short* s1,int l1,int ld1,
    const unsigned short* s2,int l2,int ld2,
    const unsigned short* W,int ldw,int ntiles,
    const float* bias, float* cbuf, unsigned short* hout, int H,
    unsigned short* encOut, int tt, int dirOff, char* smem)
{
  const int bid = blockIdx.x;
  const int mt = bid / ntiles, nt = bid % ntiles;
  const int m_base = mt*64, n_base = nt*32;
  f32x4 acc[2];
  acc[0] = (f32x4){0.f,0.f,0.f,0.f};
  acc[1] = (f32x4){0.f,0.f,0.f,0.f};
  gemm_tile(s0,l0,ld0, s1,l1,ld1, s2,l2,ld2, W,ldw, m_base,n_base, smem, acc);

  const int tid  = threadIdx.x;
  const int lane = tid & 63, wid = tid >> 6;
  const int wm = wid >> 1, wn = wid & 1, l16 = lane & 15, qd = lane >> 4;
  float* Gs = (float*)smem;                      // 64 x 32 fp32 gate tile
  __syncthreads();
#pragma unroll
  for (int tl = 0; tl < 2; ++tl)
#pragma unroll
    for (int r = 0; r < 4; ++r)
      Gs[(wm*32 + tl*16 + qd*4 + r)*32 + wn*16 + l16] = acc[tl][r];
  __syncthreads();
  for (int it = tid; it < 512; it += 256){
    const int u = it >> 6, bl = it & 63;
    const int n0 = n_base + u*4;
    const float gi = Gs[bl*32 + u*4 + 0] + bias[n0 + 0];
    const float gf = Gs[bl*32 + u*4 + 1] + bias[n0 + 1];
    const float gg = Gs[bl*32 + u*4 + 2] + bias[n0 + 2];
    const float go = Gs[bl*32 + u*4 + 3] + bias[n0 + 3];
    const int j = n0 >> 2;
    const int b = m_base + bl;
    const float iv = sigm(gi), fv = sigm(gf), gv = tanhf(gg), ov = sigm(go);
    const size_t cix = (size_t)b*H + j;
    const float cn = fv*cbuf[cix] + iv*gv;
    cbuf[cix] = cn;
    const float h = ov*tanhf(cn);
    const unsigned short hb = f2bf(h);
    hout[cix] = hb;
    if (encOut) encOut[((size_t)b*S + tt)*(2*ENC) + dirOff + j] = hb;
  }
}

// ---------------- encoder step (both directions) ----------------
__global__ __launch_bounds__(256) void k_enc_step(
  const unsigned short* __restrict__ emb,
  const unsigned short* hFin, unsigned short* hFout, float* cF,
  const unsigned short* hBin, unsigned short* hBout, float* cB,
  const unsigned short* __restrict__ WF, const unsigned short* __restrict__ WB,
  const float* __restrict__ bF, const float* __restrict__ bB,
  unsigned short* encOut, int t)
{
  __shared__ __align__(16) char smem[13824];
  const int dir = blockIdx.y;
  const int tt = dir ? (S-1-t) : t;
  const unsigned short* embt = emb + (size_t)tt*B*EMBED;
  lstm_step_body(embt,256,256, dir?hBin:hFin,256,256, nullptr,0,0,
                 dir?WB:WF, 512, 32, dir?bB:bF, dir?cB:cF, dir?hBout:hFout,
                 256, encOut, tt, dir*256, smem);
}

// ---------------- decoder gates step ----------------
__global__ __launch_bounds__(256) void k_dec_gates(
  const unsigned short* __restrict__ win_t, const unsigned short* __restrict__ feed,
  const unsigned short* __restrict__ hin,
  const unsigned short* __restrict__ WD, const float* __restrict__ bDr,
  float* cd, unsigned short* hout)
{
  __shared__ __align__(16) char smem[13824];
  lstm_step_body(win_t,64,64, feed,512,512, hin,512,512, WD,1088,64,
                 bDr, cd, hout, 512, nullptr, 0, 0, smem);
}

// ---------------- plain GEMM (bf16 out, optional tanh) ----------------
__global__ __launch_bounds__(256) void k_gemm_plain(
  const unsigned short* __restrict__ s0,int l0,int ld0,
  const unsigned short* __restrict__ s1,int l1,int ld1,
  const unsigned short* __restrict__ W,int ldw,int ntiles,
  unsigned short* Cbf, int ldc, int dotanh)
{
  __shared__ __align__(16) char smem[13824];
  const int bid = blockIdx.x;
  const int mt = bid / ntiles, nt = bid % ntiles;
  const int m_base = mt*64, n_base = nt*32;
  f32x4 acc[2];
  acc[0] = (f32x4){0.f,0.f,0.f,0.f};
  acc[1] = (f32x4){0.f,0.f,0.f,0.f};
  gemm_tile(s0,l0,ld0, s1,l1,ld1, nullptr,0,0, W,ldw, m_base,n_base, smem, acc);
  const int tid = threadIdx.x, lane = tid & 63, wid = tid >> 6;
  const int wm = wid >> 1, wn = wid & 1, l16 = lane & 15, qd = lane >> 4;
#pragma unroll
  for (int tl = 0; tl < 2; ++tl)
#pragma unroll
    for (int r = 0; r < 4; ++r){
      float v = acc[tl][r];
      if (dotanh) v = tanhf(v);
      const int m = m_base + wm*32 + tl*16 + qd*4 + r;
      Cbf[(size_t)m*ldc + n_base + wn*16 + l16] = f2bf(v);
    }
}

// ---------------- out-projection helper (tiny, per-batch block) ----------------
static __device__ __forceinline__ void outproj_body(
  int b, int tid, const unsigned short* feed, const float* W_out,
  const float* b_out, float* out_main, int tindex, float* red)
{
  float p0=0,p1=0,p2=0,p3=0;
#pragma unroll
  for (int i = 0; i < 2; ++i){
    const int k = tid + (i<<8);
    const float fv = bf2f(feed[(size_t)b*512 + k]);
    p0 += fv * W_out[k];
    p1 += fv * W_out[512 + k];
    p2 += fv * W_out[1024 + k];
    p3 += fv * W_out[1536 + k];
  }
  float pv[4] = {p0,p1,p2,p3};
  for (int d = 0; d < 4; ++d){
    __syncthreads();
    red[tid] = pv[d]; __syncthreads();
    for (int o = 128; o > 0; o >>= 1){ if (tid < o) red[tid] += red[tid+o]; __syncthreads(); }
    if (tid == 0){
      const float v = red[0] + b_out[d];
      out_main[((size_t)b*T + tindex)*4 + d] = (d < 3) ? tanhf(v) : fmaxf(v, 0.f);
    }
  }
  __syncthreads();
}

// ---------------- attention (+ fused prev-step out-proj) ----------------
__global__ __launch_bounds__(256) void k_attn(
  const unsigned short* __restrict__ hdec,    // h_t  (B,512) bf16
  const unsigned short* __restrict__ proj,    // (B,S,512) bf16
  const unsigned short* __restrict__ encOut,  // (B,S,512) bf16
  const int* __restrict__ in_seq,
  const unsigned short* __restrict__ feed,    // feed_{t-1}
  const float* __restrict__ W_out, const float* __restrict__ b_out,
  unsigned short* ctxbuf, float* out_main, float* out_attn, int t)
{
  const int b = blockIdx.x;
  const int tid = threadIdx.x;
  __shared__ float hsh[512];
  __shared__ float red[256];
  __shared__ float awsh[256];

  if (t > 0) outproj_body(b, tid, feed, W_out, b_out, out_main, t-1, red);

  hsh[tid]       = bf2f(hdec[(size_t)b*512 + tid]);
  hsh[tid + 256] = bf2f(hdec[(size_t)b*512 + tid + 256]);
  __syncthreads();

  // scores[s] = h . proj[b,s,:]  (Luong general, no scaling)
  const int s = tid;
  const uint4* pr = (const uint4*)(proj + ((size_t)b*256 + s)*512);
  float sc = 0.f;
#pragma unroll 4
  for (int i = 0; i < 64; ++i){
    const uint4 u = pr[i];
    float f0,f1,f2,f3,f4,f5,f6,f7;
    unp2(u.x,f0,f1); unp2(u.y,f2,f3); unp2(u.z,f4,f5); unp2(u.w,f6,f7);
    const float* hh = &hsh[i*8];
    sc += hh[0]*f0 + hh[1]*f1 + hh[2]*f2 + hh[3]*f3
        + hh[4]*f4 + hh[5]*f5 + hh[6]*f6 + hh[7]*f7;
  }
  if (in_seq[b*S + s] == 0) sc = -1e30f;   // mask

  // softmax over s
  red[tid] = sc; __syncthreads();
  for (int o = 128; o > 0; o >>= 1){ if (tid < o) red[tid] = fmaxf(red[tid], red[tid+o]); __syncthreads(); }
  const float mx = red[0]; __syncthreads();
  const float e = __expf(sc - mx);
  red[tid] = e; __syncthreads();
  for (int o = 128; o > 0; o >>= 1){ if (tid < o) red[tid] += red[tid+o]; __syncthreads(); }
  const float aw = e / red[0];
  awsh[s] = aw;
  out_attn[((size_t)b*T + t)*S + s] = aw;
  __syncthreads();

  // ctx[e] = sum_s aw[s] * enc_out[b,s,e]
  float a0 = 0.f, a1 = 0.f;
  for (int ss = 0; ss < 256; ++ss){
    const float w = awsh[ss];
    const unsigned short* er = encOut + ((size_t)b*256 + ss)*512;
    a0 += w * bf2f(er[tid]);
    a1 += w * bf2f(er[tid + 256]);
  }
  ctxbuf[(size_t)b*512 + tid]       = f2bf(a0);
  ctxbuf[(size_t)b*512 + tid + 256] = f2bf(a1);
}

__global__ __launch_bounds__(256) void k_outproj_final(
  const unsigned short* __restrict__ feed, const float* __restrict__ W_out,
  const float* __restrict__ b_out, float* out_main)
{
  __shared__ float red[256];
  outproj_body(blockIdx.x, threadIdx.x, feed, W_out, b_out, out_main, T-1, red);
}

// ---------------- setup / builder kernels ----------------
__global__ __launch_bounds__(256) void k_build_encw(
  const float* __restrict__ WihF, const float* __restrict__ WhhF,
  const float* __restrict__ WihB, const float* __restrict__ WhhB,
  unsigned short* WF, unsigned short* WB)
{
  const int idx = blockIdx.x*256 + threadIdx.x;     // 2*1024*512
  const int dir = idx >> 19;
  const int i2 = idx & 524287;
  const int row = i2 >> 9, col = i2 & 511;
  const int j = row >> 2, g = row & 3;
  const int orig = g*256 + j;
  const float* Wih = dir ? WihB : WihF;
  const float* Whh = dir ? WhhB : WhhF;
  const float v = (col < 256) ? Wih[orig*256 + col] : Whh[orig*256 + (col-256)];
  (dir ? WB : WF)[i2] = f2bf(v);
}

__global__ __launch_bounds__(256) void k_build_decw(
  const float* __restrict__ Wih, const float* __restrict__ Whh, unsigned short* WD)
{
  const int idx = blockIdx.x*256 + threadIdx.x;
  if (idx >= 2048*1088) return;
  const int row = idx / 1088, col = idx - row*1088;
  const int j = row >> 2, g = row & 3;
  const int orig = g*512 + j;
  float v;
  if (col < 16)        v = Wih[orig*528 + col];          // w_t part
  else if (col < 64)   v = 0.f;                          // pad
  else if (col < 576)  v = Wih[orig*528 + (col - 48)];   // feed part (cols 16..527)
  else                 v = Whh[orig*512 + (col - 576)];  // h part
  WD[idx] = f2bf(v);
}

__global__ __launch_bounds__(256) void k_build_plainw(
  const float* __restrict__ Wctx, const float* __restrict__ Wsrc,
  unsigned short* WC, unsigned short* WS)
{
  const int idx = blockIdx.x*256 + threadIdx.x;     // 512*1024 + 512*512
  if (idx < 524288) WC[idx] = f2bf(Wctx[idx]);
  else { const int i = idx - 524288; WS[i] = f2bf(Wsrc[i]); }
}

__global__ __launch_bounds__(256) void k_build_bias(
  const float* __restrict__ ebF, const float* __restrict__ ebB,
  const float* __restrict__ dB, float* bF, float* bB, float* bD)
{
  const int idx = blockIdx.x*256 + threadIdx.x;     // 4096
  if (idx < 1024) bF[idx] = ebF[(idx&3)*256 + (idx>>2)];
  else if (idx < 2048){ const int i = idx-1024; bB[i] = ebB[(i&3)*256 + (i>>2)]; }
  else { const int i = idx-2048; bD[i] = dB[(i&3)*512 + (i>>2)]; }
}

__global__ __launch_bounds__(256) void k_embed(
  const int* __restrict__ in_seq, const float* __restrict__ table, unsigned short* emb)
{
  const int idx = blockIdx.x*256 + threadIdx.x;     // S*B*256, layout (S,B,E)
  const int e = idx & 255, b = (idx >> 8) & 127, s = idx >> 15;
  const int tok = in_seq[b*S + s];
  emb[idx] = f2bf(table[(size_t)tok*256 + e]);
}

__global__ __launch_bounds__(256) void k_win(
  const float* __restrict__ tgt, unsigned short* win)
{
  const int idx = blockIdx.x*256 + threadIdx.x;     // T*B*64, layout (T,B,64)
  const int c = idx & 63, b = (idx >> 6) & 127, t = idx >> 13;
  float v = 0.f;
  if (c < 16){
    const int k = c >> 2, jj = c & 3;
    const int ts = t + k - 4;
    if (ts >= 0) v = tgt[((size_t)b*T + ts)*4 + jj];
  }
  win[idx] = f2bf(v);
}

// ---------------------------------------------------------------------------
extern "C" void kernel_launch(void* const* d_in, const int* in_sizes, int n_in,
                              void* d_out, int out_size, void* d_ws, size_t ws_size,
                              hipStream_t stream)
{
  const int*   in_seq    = (const int*)d_in[0];
  const float* tgt       = (const float*)d_in[1];
  // d_in[2] = lengths (unused by reference)
  const float* embedding = (const float*)d_in[3];
  const float* eWihF = (const float*)d_in[4];
  const float* eWhhF = (const float*)d_in[5];
  const float* ebF   = (const float*)d_in[6];
  const float* eWihB = (const float*)d_in[7];
  const float* eWhhB = (const float*)d_in[8];
  const float* ebB   = (const float*)d_in[9];
  const float* dWih  = (const float*)d_in[10];
  const float* dWhh  = (const float*)d_in[11];
  const float* dB    = (const float*)d_in[12];
  const float* Wsrc  = (const float*)d_in[13];
  const float* Wctx  = (const float*)d_in[14];
  const float* Wout  = (const float*)d_in[15];
  const float* bout  = (const float*)d_in[16];

  char* ws = (char*)d_ws;
  size_t off = 0;
  auto al = [&](size_t bytes)->char*{
    char* p = ws + off; off += (bytes + 255) & ~(size_t)255; return p; };

  // --- state region (zeroed every launch with one memset) ---
  char* stateBase = ws;
  unsigned short* hFb[2]; unsigned short* hBb[2]; unsigned short* hdb[2];
  hFb[0] = (unsigned short*)al(65536);
  hFb[1] = (unsigned short*)al(65536);
  hBb[0] = (unsigned short*)al(65536);
  hBb[1] = (unsigned short*)al(65536);
  hdb[0] = (unsigned short*)al(131072);
  hdb[1] = (unsigned short*)al(131072);
  unsigned short* feed = (unsigned short*)al(131072);
  unsigned short* ctx  = (unsigned short*)al(131072);
  float* cF = (float*)al(131072);
  float* cB = (float*)al(131072);
  float* cd = (float*)al(262144);
  const size_t stateBytes = off;

  // --- persistent-per-launch scratch ---
  unsigned short* emb    = (unsigned short*)al(16777216);  // (S,B,256) bf16
  unsigned short* win    = (unsigned short*)al(4194304);   // (T,B,64) bf16 (padded)
  unsigned short* encOut = (unsigned short*)al(33554432);  // (B,S,512) bf16
  unsigned short* proj   = (unsigned short*)al(33554432);  // (B,S,512) bf16
  unsigned short* WF     = (unsigned short*)al(1048576);   // 1024x512
  unsigned short* WB     = (unsigned short*)al(1048576);
  unsigned short* WD     = (unsigned short*)al(4456448);   // 2048x1088
  unsigned short* WC     = (unsigned short*)al(1048576);   // 512x1024
  unsigned short* WS     = (unsigned short*)al(524288);    // 512x512
  float* bFr = (float*)al(4096);
  float* bBr = (float*)al(4096);
  float* bDr = (float*)al(8192);
  (void)ws_size; (void)in_sizes; (void)n_in; (void)out_size;

  float* out_main = (float*)d_out;
  float* out_attn = out_main + (size_t)B*T*DOF;

  const dim3 blk(256);
  // setup
  k_build_encw  <<<4096,  blk, 0, stream>>>(eWihF, eWhhF, eWihB, eWhhB, WF, WB);
  k_build_decw  <<<8704,  blk, 0, stream>>>(dWih, dWhh, WD);
  k_build_plainw<<<3072,  blk, 0, stream>>>(Wctx, Wsrc, WC, WS);
  k_build_bias  <<<16,    blk, 0, stream>>>(ebF, ebB, dB, bFr, bBr, bDr);
  k_embed       <<<32768, blk, 0, stream>>>(in_seq, embedding, emb);
  k_win         <<<8192,  blk, 0, stream>>>(tgt, win);
  hipMemsetAsync(stateBase, 0, stateBytes, stream);

  // encoder: 256 steps, both directions per launch
  for (int t = 0; t < S; ++t){
    k_enc_step<<<dim3(64,2), blk, 0, stream>>>(
      emb, hFb[t&1], hFb[(t+1)&1], cF, hBb[t&1], hBb[(t+1)&1], cB,
      WF, WB, bFr, bBr, encOut, t);
  }

  // proj = enc_out @ W_src^T  (M=32768, N=512, K=512)
  k_gemm_plain<<<8192, blk, 0, stream>>>(encOut, 512, 512, nullptr, 0, 0,
                                         WS, 512, 16, proj, 512, 0);

  // decoder: 256 steps
  for (int t = 0; t < T; ++t){
    const unsigned short* hin = hdb[t&1];
    unsigned short* hnew = hdb[(t+1)&1];
    k_dec_gates<<<128, blk, 0, stream>>>(win + (size_t)t*B*64, feed, hin,
                                         WD, bDr, cd, hnew);
    k_attn<<<128, blk, 0, stream>>>(hnew, proj, encOut, in_seq, feed,
                                    Wout, bout, ctx, out_main, out_attn, t);
    // feed = tanh([h|ctx] @ W_ctx^T)  (M=128, N=512, K=1024)
    k_gemm_plain<<<32, blk, 0, stream>>>(hnew, 512, 512, ctx, 512, 512,
                                         WC, 1024, 16, feed, 512, 1);
  }
  k_outproj_final<<<128, blk, 0, stream>>>(feed, Wout, bout, out_main);
}